// Round 5
// baseline (327.404 us; speedup 1.0000x reference)
//
#include <hip/hip_runtime.h>
#include <hip/hip_fp16.h>
#include <math.h>

#define NN 2048
#define MM 32
#define DD 768
#define HH 512
#define KT 24   // 768 / 32 k-tiles
constexpr float TEMP = 0.05f;
constexpr float THRESH = 1e-4f;
constexpr float EPS = 1e-6f;

typedef _Float16 halfx8 __attribute__((ext_vector_type(8)));
typedef float floatx4 __attribute__((ext_vector_type(4)));

// ---------------------------------------------------------------------------
// prep_W: convert 3 W1 blocks (a: rows 0.., c: 1536.., d: 2304..) to fp16
// frag-ordered Wf[wb][kt][nt][lane][j] = W1[rowbase + kt*32 + (lane>>4)*8 + j]
//                                          [nt*16 + (lane&15)]
// Grid 72 = 3 wb x 24 kt.
// ---------------------------------------------------------------------------
__global__ __launch_bounds__(256) void prep_W_kernel(
    const float* __restrict__ W1, _Float16* __restrict__ Wf)
{
    __shared__ float Wt[32 * 512];   // 64 KB
    const int wb = blockIdx.x / 24;
    const int kt = blockIdx.x % 24;
    const int rowbase = (wb == 0) ? 0 : (wb == 1 ? 1536 : 2304);
    const int t = threadIdx.x;
    #pragma unroll
    for (int rep = 0; rep < 16; ++rep) {
        int idx = rep * 256 + t;
        int row = idx >> 7;
        int c4 = (idx & 127) * 4;
        *(float4*)&Wt[row * 512 + c4] =
            *(const float4*)(W1 + (size_t)(rowbase + kt * 32 + row) * HH + c4);
    }
    __syncthreads();
    #pragma unroll
    for (int g = 0; g < 8; ++g) {
        halfx8 v;
        #pragma unroll
        for (int jj = 0; jj < 8; ++jj) {
            int o = t * 64 + g * 8 + jj;        // o = nt*512 + l*8 + j
            int nt = o >> 9;
            int l  = (o >> 3) & 63;
            int j  = o & 7;
            int k  = ((l >> 4) << 3) + j;
            int n  = nt * 16 + (l & 15);
            v[jj] = (_Float16)Wt[k * 512 + n];
        }
        *(halfx8*)(Wf + ((size_t)wb * KT + kt) * 16384 + t * 64 + g * 8) = v;
    }
}

// ---------------------------------------------------------------------------
// build_A_mfma: Arow = X@W1a + |X-q|@W1d via 2-pass fp16-split MFMA.
// Block: 32 i x 512 h, 512 threads = 8 waves (2 row-groups x 4 col-quarters).
// Grid 64. (~12 us; hi/lo kept here for accuracy headroom.)
// ---------------------------------------------------------------------------
__global__ __launch_bounds__(512, 2) void build_A_mfma_kernel(
    const float* __restrict__ X, const float* __restrict__ q,
    const _Float16* __restrict__ Wf, float* __restrict__ Arow)
{
    __shared__ _Float16 Zh[32 * 40];
    __shared__ _Float16 Zl[32 * 40];
    __shared__ float qs[DD];
    const int t = threadIdx.x;
    const int lane = t & 63;
    const int wv = t >> 6;
    const int wr = wv >> 2;      // 0..1: rows 16*wr..
    const int wc = wv & 3;       // 0..3: cols 128*wc..
    const int q4 = lane >> 4;
    const int l16 = lane & 15;
    const int i0 = blockIdx.x * 32;

    for (int d = t; d < DD; d += 512) qs[d] = q[d];

    floatx4 acc[8];
    #pragma unroll
    for (int ct = 0; ct < 8; ++ct) acc[ct] = (floatx4)0.f;

    const int zr = t >> 4;        // 0..31
    const int zk = (t & 15) * 2;

    for (int term = 0; term < 2; ++term) {
        const _Float16* Wbase = Wf + (size_t)(term ? 2 : 0) * KT * 16384;
        for (int kt = 0; kt < KT; ++kt) {
            __syncthreads();
            {   // stage Z (32 rows x 32 k), hi/lo fp16 split
                const float* xp = X + (size_t)(i0 + zr) * DD + kt * 32 + zk;
                float2 xv = *(const float2*)xp;
                float z0 = xv.x, z1 = xv.y;
                if (term) {
                    z0 = fabsf(z0 - qs[kt * 32 + zk + 0]);
                    z1 = fabsf(z1 - qs[kt * 32 + zk + 1]);
                }
                _Float16 h0 = (_Float16)z0, h1 = (_Float16)z1;
                Zh[zr * 40 + zk + 0] = h0;
                Zh[zr * 40 + zk + 1] = h1;
                Zl[zr * 40 + zk + 0] = (_Float16)(z0 - (float)h0);
                Zl[zr * 40 + zk + 1] = (_Float16)(z1 - (float)h1);
            }
            __syncthreads();
            halfx8 Ah = *(halfx8*)&Zh[(wr * 16 + l16) * 40 + q4 * 8];
            halfx8 Al = *(halfx8*)&Zl[(wr * 16 + l16) * 40 + q4 * 8];
            const _Float16* wp = Wbase + (size_t)kt * 16384
                                 + (size_t)(wc * 8) * 512 + lane * 8;
            #pragma unroll
            for (int ct = 0; ct < 8; ++ct) {
                halfx8 B = *(const halfx8*)(wp + (size_t)ct * 512);
                acc[ct] = __builtin_amdgcn_mfma_f32_16x16x32_f16(Ah, B, acc[ct], 0, 0, 0);
                acc[ct] = __builtin_amdgcn_mfma_f32_16x16x32_f16(Al, B, acc[ct], 0, 0, 0);
            }
        }
    }
    #pragma unroll
    for (int ct = 0; ct < 8; ++ct)
        #pragma unroll
        for (int reg = 0; reg < 4; ++reg) {
            int row = wr * 16 + q4 * 4 + reg;
            int h = wc * 128 + ct * 16 + l16;
            Arow[(size_t)(i0 + row) * HH + h] = acc[ct][reg];
        }
}

// ---------------------------------------------------------------------------
// build_B: Brow[j][h] = b1[h] + y@W1b + |y-q|@W1e. Grid (32 j, 2 h-chunks).
// ---------------------------------------------------------------------------
__global__ __launch_bounds__(256) void build_B_kernel(
    const float* __restrict__ C_init, const float* __restrict__ q,
    const float* __restrict__ W1, const float* __restrict__ b1,
    float* __restrict__ Brow)
{
    __shared__ float ys[DD], ya[DD];
    const int j = blockIdx.x, t = threadIdx.x;
    const int h = blockIdx.y * 256 + t;
    for (int idx = t; idx < DD; idx += 256) {
        float y = C_init[(size_t)j * DD + idx];
        ys[idx] = y;
        ya[idx] = fabsf(y - q[idx]);
    }
    __syncthreads();
    const float* W1b = W1 + (size_t)768 * HH + h;
    const float* W1e = W1 + (size_t)3072 * HH + h;
    float acc = b1[h];
    #pragma unroll 8
    for (int d = 0; d < DD; ++d)
        acc = fmaf(ys[d], W1b[(size_t)d * HH], fmaf(ya[d], W1e[(size_t)d * HH], acc));
    Brow[(size_t)j * HH + h] = acc;
}

// ---------------------------------------------------------------------------
// pairwise_mfma: P = |X - y_j| @ W1c, single-pass fp16 MFMA (Z hi only),
// fused epilogue s[i,j] = sum_h relu(P + A + B) * W2[h].
// Block: 128 i x 512 h, 8 waves = 2 row-groups(64i) x 4 col-quarters(128h).
// Wave: 64i x 128h = 4 rowtiles x 8 coltiles -> each B-frag feeds 4 MFMAs.
// Grid (16, 32).
// ---------------------------------------------------------------------------
__global__ __launch_bounds__(512, 2) void pairwise_mfma_kernel(
    const float* __restrict__ X, const _Float16* __restrict__ Wf,
    const float* __restrict__ Y,
    const float* __restrict__ Arow, const float* __restrict__ Brow,
    const float* __restrict__ W2, float* __restrict__ S)
{
    __shared__ _Float16 Zh[128 * 40];   // 10 KB
    __shared__ float ys[DD];            // 3 KB
    __shared__ float Sred[4 * 128];     // 2 KB
    const int t = threadIdx.x;
    const int lane = t & 63;
    const int wv = t >> 6;
    const int wr = wv >> 2;      // 0..1: rows 64*wr..
    const int cq = wv & 3;       // 0..3: cols 128*cq..
    const int q4 = lane >> 4;
    const int l16 = lane & 15;
    const int i0 = blockIdx.x * 128;
    const int j  = blockIdx.y;

    for (int d = t; d < DD; d += 512) ys[d] = Y[(size_t)j * DD + d];

    const _Float16* Wc = Wf + (size_t)1 * KT * 16384;

    floatx4 acc[4][8];
    #pragma unroll
    for (int rt = 0; rt < 4; ++rt)
        #pragma unroll
        for (int ct = 0; ct < 8; ++ct) acc[rt][ct] = (floatx4)0.f;

    const int zr = t >> 2;        // 0..127
    const int zk = (t & 3) * 8;

    for (int kt = 0; kt < KT; ++kt) {
        __syncthreads();
        {   // stage Z = |x - y| as fp16 (single pass)
            const float* xp = X + (size_t)(i0 + zr) * DD + kt * 32 + zk;
            float4 xa = *(const float4*)xp;
            float4 xb = *(const float4*)(xp + 4);
            halfx8 vh;
            vh[0] = (_Float16)fabsf(xa.x - ys[kt * 32 + zk + 0]);
            vh[1] = (_Float16)fabsf(xa.y - ys[kt * 32 + zk + 1]);
            vh[2] = (_Float16)fabsf(xa.z - ys[kt * 32 + zk + 2]);
            vh[3] = (_Float16)fabsf(xa.w - ys[kt * 32 + zk + 3]);
            vh[4] = (_Float16)fabsf(xb.x - ys[kt * 32 + zk + 4]);
            vh[5] = (_Float16)fabsf(xb.y - ys[kt * 32 + zk + 5]);
            vh[6] = (_Float16)fabsf(xb.z - ys[kt * 32 + zk + 6]);
            vh[7] = (_Float16)fabsf(xb.w - ys[kt * 32 + zk + 7]);
            *(halfx8*)&Zh[zr * 40 + zk] = vh;
        }
        __syncthreads();

        halfx8 Ah[4];
        #pragma unroll
        for (int rt = 0; rt < 4; ++rt) {
            int r = wr * 64 + rt * 16 + l16;
            Ah[rt] = *(halfx8*)&Zh[r * 40 + q4 * 8];
        }
        const _Float16* wp = Wc + ((size_t)kt * 16384) + (size_t)(cq * 8) * 512 + lane * 8;
        #pragma unroll
        for (int ct = 0; ct < 8; ++ct) {
            halfx8 B = *(const halfx8*)(wp + (size_t)ct * 512);
            #pragma unroll
            for (int rt = 0; rt < 4; ++rt)
                acc[rt][ct] = __builtin_amdgcn_mfma_f32_16x16x32_f16(Ah[rt], B, acc[rt][ct], 0, 0, 0);
        }
    }

    // epilogue: lane holds rows wr*64+rt*16+q4*4+reg, col h = cq*128+ct*16+l16
    float w2v[8], bv[8];
    #pragma unroll
    for (int ct = 0; ct < 8; ++ct) {
        int h = cq * 128 + ct * 16 + l16;
        w2v[ct] = W2[h];
        bv[ct]  = Brow[(size_t)j * HH + h];
    }
    #pragma unroll
    for (int rt = 0; rt < 4; ++rt) {
        #pragma unroll
        for (int reg = 0; reg < 4; ++reg) {
            int row = wr * 64 + rt * 16 + q4 * 4 + reg;
            const float* ap = Arow + (size_t)(i0 + row) * HH + cq * 128 + l16;
            float s = 0.f;
            #pragma unroll
            for (int ct = 0; ct < 8; ++ct) {
                float pre = acc[rt][ct][reg] + ap[ct * 16] + bv[ct];
                s = fmaf(fmaxf(pre, 0.f), w2v[ct], s);
            }
            s += __shfl_xor(s, 1, 64);
            s += __shfl_xor(s, 2, 64);
            s += __shfl_xor(s, 4, 64);
            s += __shfl_xor(s, 8, 64);
            if (l16 == 0) Sred[cq * 128 + row] = s;
        }
    }
    __syncthreads();
    if (t < 128)
        S[(size_t)(i0 + t) * MM + j] =
            Sred[t] + Sred[128 + t] + Sred[256 + t] + Sred[384 + t];
}

// ---------------------------------------------------------------------------
__global__ __launch_bounds__(256) void softmax_kernel(
    const float* __restrict__ S, const float* __restrict__ b2,
    float* __restrict__ a_out)
{
    const int t = threadIdx.x;
    const int j = t & 31, r = t >> 5;
    const int i = blockIdx.x * 8 + r;
    const float b2v = b2[0];
    float s = S[(size_t)i * MM + j];
    float sig = 1.f / (1.f + expf(-(s + b2v)));
    float l = -sig * (1.0f / TEMP);
    float m = l;
    #pragma unroll
    for (int off = 16; off >= 1; off >>= 1) m = fmaxf(m, __shfl_xor(m, off, 32));
    float e = expf(l - m);
    float sum = e;
    #pragma unroll
    for (int off = 16; off >= 1; off >>= 1) sum += __shfl_xor(sum, off, 32);
    a_out[(size_t)i * MM + j] = e / sum;
}

__global__ __launch_bounds__(256) void cnew_partial_kernel(
    const float* __restrict__ a, const float* __restrict__ X,
    float* __restrict__ Cacc, float* __restrict__ Asum)
{
    const int t = threadIdx.x;
    const int d = blockIdx.x * 256 + t;
    const int j = blockIdx.y;
    const int i0 = blockIdx.z * 256;
    float acc = 0.f, asum = 0.f;
    for (int ii = 0; ii < 256; ++ii) {
        float av = a[(size_t)(i0 + ii) * MM + j];
        asum += av;
        acc = fmaf(av, X[(size_t)(i0 + ii) * DD + d], acc);
    }
    atomicAdd(&Cacc[(size_t)j * DD + d], acc);
    if (blockIdx.x == 0 && t == 0) atomicAdd(&Asum[j], asum);
}

__global__ __launch_bounds__(256) void finalize_kernel(
    const float* __restrict__ Cacc, const float* __restrict__ Asum,
    const float* __restrict__ C_init, float* __restrict__ C_new,
    float* __restrict__ diff)
{
    const int t = threadIdx.x;
    const int d = blockIdx.x * 256 + t;
    const int j = blockIdx.y;
    float c = Cacc[(size_t)j * DD + d] / (Asum[j] + EPS);
    C_new[(size_t)j * DD + d] = c;
    float ad = fabsf(c - C_init[(size_t)j * DD + d]);
    #pragma unroll
    for (int off = 32; off >= 1; off >>= 1) ad += __shfl_xor(ad, off, 64);
    if ((t & 63) == 0) atomicAdd(diff, ad);
}

__global__ __launch_bounds__(256) void select_kernel(
    const float* __restrict__ C_new, const float* __restrict__ C_init,
    const float* __restrict__ diff, float* __restrict__ out)
{
    const int k = blockIdx.x * 256 + threadIdx.x;
    const float dv = *diff;
    out[k] = (dv > THRESH) ? C_new[k] : C_init[k];
}

// ---------------------------------------------------------------------------
extern "C" void kernel_launch(void* const* d_in, const int* in_sizes, int n_in,
                              void* d_out, int out_size, void* d_ws, size_t ws_size,
                              hipStream_t stream)
{
    const float* q      = (const float*)d_in[0];
    const float* X      = (const float*)d_in[1];
    const float* C_init = (const float*)d_in[2];
    const float* W1     = (const float*)d_in[3];
    const float* b1     = (const float*)d_in[4];
    const float* W2     = (const float*)d_in[5];
    const float* b2     = (const float*)d_in[6];

    float* out_C = (float*)d_out;                    // (M, D)
    float* out_a = (float*)d_out + (size_t)MM * DD;  // (N, M)

    float* ws   = (float*)d_ws;
    _Float16* Wf = (_Float16*)ws;                    // 3*24*16384 halves = 589824 floats
    float* Arow = ws + 589824;                       // N*H
    float* Brow = Arow + (size_t)NN * HH;            // M*H
    float* S    = Brow + (size_t)MM * HH;            // N*M
    float* Cacc = S    + (size_t)NN * MM;            // M*D
    float* Asum = Cacc + (size_t)MM * DD;            // M
    float* diff = Asum + MM;                         // 1 (+15 pad)
    float* Cn   = diff + 16;                         // M*D

    hipMemsetAsync(Cacc, 0, ((size_t)MM * DD + MM + 16) * sizeof(float), stream);

    prep_W_kernel<<<3 * KT, 256, 0, stream>>>(W1, Wf);
    build_B_kernel<<<dim3(32, 2), 256, 0, stream>>>(C_init, q, W1, b1, Brow);
    build_A_mfma_kernel<<<64, 512, 0, stream>>>(X, q, Wf, Arow);
    pairwise_mfma_kernel<<<dim3(16, 32), 512, 0, stream>>>(X, Wf, C_init, Arow, Brow, W2, S);
    softmax_kernel<<<256, 256, 0, stream>>>(S, b2, out_a);
    cnew_partial_kernel<<<dim3(3, 32, 8), 256, 0, stream>>>(out_a, X, Cacc, Asum);
    finalize_kernel<<<dim3(3, 32), 256, 0, stream>>>(Cacc, Asum, C_init, Cn, diff);
    select_kernel<<<96, 256, 0, stream>>>(Cn, C_init, diff, out_C);
}